// Round 1
// baseline (414.139 us; speedup 1.0000x reference)
//
#include <hip/hip_runtime.h>
#include <hip/hip_bf16.h>

// QuantizedLinear: out[64,8192] = x[64,8192] @ (alpha * ternary(W))^T + bias
// W is [O=8192, I=8192] fp32 row-major. Ternary {-1,0,+1} exact in bf16; alpha
// applied fp32 in epilogue; only x is rounded to bf16.
//
// LDS-free streaming structure: each wave loads W fp32 DIRECTLY in MFMA
// B-fragment layout (lane l: row n0+wv*16+(l&15), k=(l>>4)*8..+8 = 32 B
// contiguous), ternarizes in-register to bf16, and MFMAs against X A-frags
// loaded straight from the bf16 workspace (L2-resident, 1 MB). No __shared__,
// no __syncthreads__ -> no barrier drain; pure HBM stream of W (268 MB).

typedef __attribute__((ext_vector_type(8))) short short8;   // 8 bf16 = 4 VGPRs
typedef __attribute__((ext_vector_type(4))) float floatx4;  // MFMA acc

#define B_DIM 64
#define K_DIM 8192
#define O_DIM 8192
#define BN 64                      // n-cols per block (16 per wave)
#define KSPLIT 8
#define KCHUNK (K_DIM / KSPLIT)    // 1024 k per block
#define KSTEPS (KCHUNK / 32)       // 32 MFMA k-steps of K=32

// ---- prep: x fp32 -> bf16 workspace; out = bias broadcast (re-done every call) ----
__global__ __launch_bounds__(256) void prep_kernel(
    const float* __restrict__ x, const float* __restrict__ bias,
    __hip_bfloat16* __restrict__ xbf, float* __restrict__ out) {
  int idx = blockIdx.x * 256 + threadIdx.x;          // 0 .. 524287 (B*K == B*O)
  xbf[idx] = __float2bfloat16(x[idx]);
  out[idx] = bias[idx & (O_DIM - 1)];
}

// ---- main GEMM: 1024 blocks (128 n-tiles x 8 k-slices), 256 threads, no LDS ----
__global__ __launch_bounds__(256, 4) void gemm_kernel(
    const float* __restrict__ w, const unsigned short* __restrict__ xbf,
    const float* __restrict__ alpha, float* __restrict__ out) {
  const int tid = threadIdx.x;
  const int nt = blockIdx.x & 127;   // n-tile (fast dim -> co-resident blocks share k-chunk for X L2 reuse)
  const int ks = blockIdx.x >> 7;    // k-slice 0..7
  const int n0 = nt * BN;
  const int k0 = ks * KCHUNK;

  const int wv  = tid >> 6;    // wave 0..3 -> n-sub tile (16 cols)
  const int ln  = tid & 63;
  const int lhi = ln >> 4;     // 0..3 -> k-subgroup of 8
  const int llo = ln & 15;     // fragment row

  // This lane's W row (output col) -- B-frag layout row = lane&15.
  const int nrow = n0 + wv * 16 + llo;
  const float av  = alpha[nrow];
  const float thr = 0.5f * (av + 1e-8f);   // |w| > 0.5*(alpha+eps) -> +/-1

  // W: lane reads 8 contiguous fp32 at k = k0 + lhi*8 + kt*32 (exact B-frag map).
  const float* wp = w + (size_t)nrow * K_DIM + (size_t)(k0 + lhi * 8);
  // X: A-frag row = mt*16 + llo, k = k0 + lhi*8 + kt*32 (16 B contiguous bf16).
  const unsigned short* xp = xbf + (size_t)llo * K_DIM + (size_t)(k0 + lhi * 8);

  floatx4 acc[4];
#pragma unroll
  for (int i = 0; i < 4; ++i) acc[i] = (floatx4){0.f, 0.f, 0.f, 0.f};

  auto tern = [&](float v) -> short {
    // +1 -> 0x3F80, -1 -> 0xBF80, 0 -> 0 (bf16 bit patterns)
    return v > thr ? (short)0x3F80
                   : (v < -thr ? (short)(unsigned short)0xBF80 : (short)0);
  };

#pragma unroll 2
  for (int kt = 0; kt < KSTEPS; ++kt) {
    const float* p = wp + kt * 32;
    float4 w0 = *(const float4*)(p);
    float4 w1 = *(const float4*)(p + 4);

    const unsigned short* q = xp + kt * 32;
    short8 a0 = *(const short8*)(const void*)(q);
    short8 a1 = *(const short8*)(const void*)(q + 16 * (size_t)K_DIM);
    short8 a2 = *(const short8*)(const void*)(q + 32 * (size_t)K_DIM);
    short8 a3 = *(const short8*)(const void*)(q + 48 * (size_t)K_DIM);

    short8 b;
    b[0] = tern(w0.x); b[1] = tern(w0.y); b[2] = tern(w0.z); b[3] = tern(w0.w);
    b[4] = tern(w1.x); b[5] = tern(w1.y); b[6] = tern(w1.z); b[7] = tern(w1.w);

    acc[0] = __builtin_amdgcn_mfma_f32_16x16x32_bf16(a0, b, acc[0], 0, 0, 0);
    acc[1] = __builtin_amdgcn_mfma_f32_16x16x32_bf16(a1, b, acc[1], 0, 0, 0);
    acc[2] = __builtin_amdgcn_mfma_f32_16x16x32_bf16(a2, b, acc[2], 0, 0, 0);
    acc[3] = __builtin_amdgcn_mfma_f32_16x16x32_bf16(a3, b, acc[3], 0, 0, 0);
  }

  // epilogue: C/D layout col=lane&15 (n), row=(lane>>4)*4+reg (m); fp32 alpha scale
#pragma unroll
  for (int mt = 0; mt < 4; ++mt) {
    const int m = mt * 16 + lhi * 4;
#pragma unroll
    for (int r = 0; r < 4; ++r) {
      atomicAdd(&out[(size_t)(m + r) * O_DIM + nrow], acc[mt][r] * av);
    }
  }
}

extern "C" void kernel_launch(void* const* d_in, const int* in_sizes, int n_in,
                              void* d_out, int out_size, void* d_ws, size_t ws_size,
                              hipStream_t stream) {
  const float* x     = (const float*)d_in[0];  // [64, 8192]
  const float* w     = (const float*)d_in[1];  // [8192, 8192]
  const float* alpha = (const float*)d_in[2];  // [8192, 1]
  const float* bias  = (const float*)d_in[3];  // [8192]
  float* out = (float*)d_out;                  // [64, 8192]
  __hip_bfloat16* xbf = (__hip_bfloat16*)d_ws; // 1 MB scratch

  prep_kernel<<<(B_DIM * K_DIM) / 256, 256, 0, stream>>>(x, bias, xbf, out);
  gemm_kernel<<<(O_DIM / BN) * KSPLIT, 256, 0, stream>>>(
      w, (const unsigned short*)xbf, alpha, out);
}